// Round 1
// baseline (1012.160 us; speedup 1.0000x reference)
//
#include <hip/hip_runtime.h>
#include <math.h>

#define BB 8
#define CCH 256
#define NN 16384
#define KK 64
#define NSEG 8
#define SCALE 0.0625f   // C^-0.5 = 1/16

// workspace layout (float offsets)
constexpr size_t OFF_ATTN = 0;                                  // B*N*K = 8388608
constexpr size_t OFF_CTT  = 8388608;                            // C*K   = 16384 (centers^T [c][k])
constexpr size_t OFF_PWT  = OFF_CTT + 16384;                    // C*C   = 65536 (pw_w^T [c][o])
constexpr size_t OFF_CLU  = OFF_PWT + 65536;                    // NSEG*B*K*C = 1048576
constexpr size_t OFF_M    = OFF_CLU + (size_t)NSEG*BB*KK*CCH;   // NSEG*B*K*K = 262144
constexpr size_t OFF_AB   = OFF_M   + (size_t)NSEG*BB*KK*KK;    // NSEG*B*K   = 4096
constexpr size_t OFF_REF  = OFF_AB  + (size_t)NSEG*BB*KK;       // B*K*C = 131072
constexpr size_t OFF_G    = OFF_REF + (size_t)BB*KK*CCH;        // B*K*C = 131072
constexpr size_t OFF_MS   = OFF_G   + (size_t)BB*KK*CCH;        // B*32
constexpr size_t OFF_RS   = OFF_MS  + 256;                      // B*32

// ---------- P0: transpose centers and pw_w ----------
__global__ __launch_bounds__(256) void p0_prep(const float* __restrict__ centers,
                                               const float* __restrict__ pw_w,
                                               float* __restrict__ ws) {
    int idx = blockIdx.x * 256 + threadIdx.x;   // 0..65535
    if (idx < 16384) {
        int c = idx >> 6, k = idx & 63;
        ws[OFF_CTT + idx] = centers[k * CCH + c];
    }
    int c = idx >> 8, o = idx & 255;
    ws[OFF_PWT + idx] = pw_w[o * CCH + c];
}

// ---------- P1: sim -> softmax -> attn, abar, M, cluster ----------
__global__ __launch_bounds__(256) void p1_attn(const float* __restrict__ x,
                                               float* __restrict__ ws) {
    __shared__ float xs[64][65];   // [n_local][c_chunk]
    __shared__ float cs[64][68];   // [c_chunk][k]
    __shared__ float at[64][68];   // sim -> attn [n][k]
    __shared__ float rinv[64];

    const int tid = threadIdx.x;
    const int b = blockIdx.y;
    const int n0 = blockIdx.x * 64;
    const int seg = blockIdx.x & (NSEG - 1);
    const int nt = tid & 15, kt = tid >> 4;     // 16 x 16 micro-tile grid
    const int cl0 = tid >> 6;                   // 0..3
    const int nl  = tid & 63;

    const float* ctT = ws + OFF_CTT;
    float* attn_g = ws + OFF_ATTN;
    float* clu = ws + OFF_CLU;
    float* Mg  = ws + OFF_M;
    float* ab  = ws + OFF_AB;

    float acc[16];
#pragma unroll
    for (int i = 0; i < 16; ++i) acc[i] = 0.f;

    // ---- sim = x^T centers^T over 4 c-chunks ----
    for (int cc = 0; cc < 4; ++cc) {
#pragma unroll 4
        for (int it = 0; it < 16; ++it) {
            int c = it * 4 + cl0;
            xs[nl][c] = x[((size_t)(b * CCH + cc * 64 + c)) * NN + n0 + nl];
        }
#pragma unroll 4
        for (int it = 0; it < 16; ++it) {
            int c = it * 4 + cl0;
            cs[c][nl] = ctT[(cc * 64 + c) * KK + nl];
        }
        __syncthreads();
#pragma unroll 4
        for (int c = 0; c < 64; ++c) {
            float xv[4];
#pragma unroll
            for (int i = 0; i < 4; ++i) xv[i] = xs[4 * nt + i][c];
            float4 cv = *(const float4*)&cs[c][4 * kt];
            float cva[4] = {cv.x, cv.y, cv.z, cv.w};
#pragma unroll
            for (int i = 0; i < 4; ++i)
#pragma unroll
                for (int j = 0; j < 4; ++j)
                    acc[i * 4 + j] += xv[i] * cva[j];
        }
        __syncthreads();
    }
    // store sims to LDS
#pragma unroll
    for (int i = 0; i < 4; ++i) {
        float4 v = make_float4(acc[i * 4 + 0], acc[i * 4 + 1], acc[i * 4 + 2], acc[i * 4 + 3]);
        *(float4*)&at[4 * nt + i][4 * kt] = v;
    }
    __syncthreads();

    // ---- softmax over k (one thread per n) ----
    if (tid < 64) {
        int n = tid;
        float mx = -1e30f;
#pragma unroll 8
        for (int k = 0; k < 64; ++k) mx = fmaxf(mx, at[n][k] * SCALE);
        float sum = 0.f;
#pragma unroll 8
        for (int k = 0; k < 64; ++k) {
            float e = expf(at[n][k] * SCALE - mx);
            at[n][k] = e;
            sum += e;
        }
        rinv[n] = 1.f / sum;
    }
    __syncthreads();

    // ---- normalize + write attn to global ----
    {
        int n = tid >> 2;
        int k0 = (tid & 3) * 16;
        float r = rinv[n];
        float* gdst = attn_g + ((size_t)b * NN + n0 + n) * KK + k0;
#pragma unroll
        for (int m4 = 0; m4 < 4; ++m4) {
            float4 v = *(float4*)&at[n][k0 + 4 * m4];
            v.x *= r; v.y *= r; v.z *= r; v.w *= r;
            *(float4*)&at[n][k0 + 4 * m4] = v;
            *(float4*)(gdst + 4 * m4) = v;
        }
    }
    __syncthreads();

    // ---- abar partial ----
    if (tid < 64) {
        int k = tid;
        float s = 0.f;
#pragma unroll 8
        for (int n = 0; n < 64; ++n) s += at[n][k];
        atomicAdd(&ab[(size_t)(seg * BB + b) * KK + k], s * (1.0f / 16384.0f));
    }

    // ---- M partial: M[k2][k1] += sum_n a[n][k2] a[n][k1] ----
    {
        float accm[16];
#pragma unroll
        for (int i = 0; i < 16; ++i) accm[i] = 0.f;
#pragma unroll 4
        for (int n = 0; n < 64; ++n) {
            float4 a1 = *(float4*)&at[n][4 * nt];
            float4 a2 = *(float4*)&at[n][4 * kt];
            float a1a[4] = {a1.x, a1.y, a1.z, a1.w};
            float a2a[4] = {a2.x, a2.y, a2.z, a2.w};
#pragma unroll
            for (int i = 0; i < 4; ++i)
#pragma unroll
                for (int j = 0; j < 4; ++j)
                    accm[i * 4 + j] += a2a[i] * a1a[j];
        }
        float* Mb = Mg + (size_t)(seg * BB + b) * KK * KK;
#pragma unroll
        for (int i = 0; i < 4; ++i)
#pragma unroll
            for (int j = 0; j < 4; ++j)
                atomicAdd(&Mb[(4 * kt + i) * KK + 4 * nt + j], accm[i * 4 + j]);
    }

    // ---- cluster partial: clu[k][c] += sum_n a[n][k] x[n][c] ----
    for (int cc = 0; cc < 4; ++cc) {
        __syncthreads();
#pragma unroll 4
        for (int it = 0; it < 16; ++it) {
            int c = it * 4 + cl0;
            xs[nl][c] = x[((size_t)(b * CCH + cc * 64 + c)) * NN + n0 + nl];
        }
        __syncthreads();
        float accc[16];
#pragma unroll
        for (int i = 0; i < 16; ++i) accc[i] = 0.f;
#pragma unroll 4
        for (int n = 0; n < 64; ++n) {
            float4 av = *(float4*)&at[n][4 * nt];   // k dims
            float ava[4] = {av.x, av.y, av.z, av.w};
            float xv[4];
#pragma unroll
            for (int j = 0; j < 4; ++j) xv[j] = xs[n][4 * kt + j];   // c dims
#pragma unroll
            for (int i = 0; i < 4; ++i)
#pragma unroll
                for (int j = 0; j < 4; ++j)
                    accc[i * 4 + j] += ava[i] * xv[j];
        }
        float* cb = clu + (size_t)(seg * BB + b) * KK * CCH;
#pragma unroll
        for (int i = 0; i < 4; ++i)
#pragma unroll
            for (int j = 0; j < 4; ++j)
                atomicAdd(&cb[(4 * nt + i) * CCH + cc * 64 + 4 * kt + j], accc[i * 4 + j]);
    }
}

// ---------- P2a: segment-sum cluster, depthwise 7x7 + bias + silu ----------
__global__ __launch_bounds__(256) void p2_dw(const float* __restrict__ dw_w,
                                             const float* __restrict__ dw_b,
                                             float* __restrict__ ws) {
    __shared__ float clu_s[64][256];   // 64 KB
    const int b = blockIdx.y;
    const int kq = blockIdx.x;         // 0..3 -> k range kq*16..+16
    const int tid = threadIdx.x;       // = channel c
    const float* clu = ws + OFF_CLU;
    float* ref = ws + OFF_REF;

    for (int k = 0; k < 64; ++k) {
        float s = 0.f;
#pragma unroll
        for (int sg = 0; sg < NSEG; ++sg)
            s += clu[((size_t)(sg * BB + b) * KK + k) * CCH + tid];
        clu_s[k][tid] = s;
    }
    float w[49];
#pragma unroll
    for (int t = 0; t < 49; ++t) w[t] = dw_w[tid * 49 + t];
    float bias = dw_b[tid];
    __syncthreads();

    for (int it = 0; it < 16; ++it) {
        int k = kq * 16 + it;
        int ky = k >> 3, kx = k & 7;
        float v = 0.f;
#pragma unroll
        for (int dy = 0; dy < 7; ++dy) {
            int yy = ky + dy - 3;
            if (yy < 0 || yy > 7) continue;
#pragma unroll
            for (int dx = 0; dx < 7; ++dx) {
                int xx = kx + dx - 3;
                if (xx < 0 || xx > 7) continue;
                v += clu_s[yy * 8 + xx][tid] * w[dy * 7 + dx];
            }
        }
        v += bias;
        float sv = v / (1.f + expf(-v));   // silu
        ref[((size_t)b * KK + k) * CCH + tid] = sv;
    }
}

// ---------- P2b: G[b,k,o] = sum_c refined[b,k,c] * pw_w[o,c] + pw_b[o] ----------
__global__ __launch_bounds__(256) void p2_g(const float* __restrict__ pw_b,
                                            float* __restrict__ ws) {
    __shared__ float rs[256];
    const int b = blockIdx.y, k = blockIdx.x, tid = threadIdx.x;
    const float* ref = ws + OFF_REF;
    const float* pwT = ws + OFF_PWT;
    float* G = ws + OFF_G;
    rs[tid] = ref[((size_t)b * KK + k) * CCH + tid];
    __syncthreads();
    float g = pw_b[tid];
#pragma unroll 8
    for (int c = 0; c < 256; ++c)
        g += rs[c] * pwT[c * CCH + tid];
    G[((size_t)b * KK + k) * CCH + tid] = g;
}

// ---------- P2c: analytic group-norm statistics ----------
__global__ __launch_bounds__(256) void p2_stats(float* __restrict__ ws) {
    __shared__ float Ms[4096];
    __shared__ float abs_[64];
    __shared__ float mu_s[256];
    __shared__ float q_s[256];
    const int b = blockIdx.x, tid = threadIdx.x;
    const float* Mg = ws + OFF_M;
    const float* ab = ws + OFF_AB;
    const float* G = ws + OFF_G;

    for (int it = 0; it < 16; ++it) {
        int idx = it * 256 + tid;
        float s = 0.f;
#pragma unroll
        for (int sg = 0; sg < NSEG; ++sg)
            s += Mg[(size_t)(sg * BB + b) * 4096 + idx];
        Ms[idx] = s * (1.0f / 16384.0f);   // M / N
    }
    if (tid < 64) {
        float s = 0.f;
#pragma unroll
        for (int sg = 0; sg < NSEG; ++sg)
            s += ab[(size_t)(sg * BB + b) * KK + tid];
        abs_[tid] = s;
    }
    __syncthreads();

    float gv[64];
#pragma unroll 8
    for (int k = 0; k < 64; ++k) gv[k] = G[((size_t)b * KK + k) * CCH + tid];
    float mu = 0.f;
#pragma unroll 8
    for (int k = 0; k < 64; ++k) mu += abs_[k] * gv[k];
    float q = 0.f;
    for (int k = 0; k < 64; ++k) {
        float t = 0.f;
#pragma unroll 8
        for (int k2 = 0; k2 < 64; ++k2) t += Ms[k * 64 + k2] * gv[k2];
        q += t * gv[k];
    }
    mu_s[tid] = mu;
    q_s[tid] = q;
    __syncthreads();
    if (tid < 32) {
        float m = 0.f, e = 0.f;
#pragma unroll
        for (int j = 0; j < 8; ++j) { m += mu_s[tid * 8 + j]; e += q_s[tid * 8 + j]; }
        m *= 0.125f; e *= 0.125f;
        float var = e - m * m;
        ws[OFF_MS + b * 32 + tid] = m;
        ws[OFF_RS + b * 32 + tid] = rsqrtf(fmaxf(var, 0.f) + 1e-5f);
    }
}

// ---------- P3: y = attn @ G ; out = x + (y-m)*rsig*gamma + beta ----------
__global__ __launch_bounds__(256) void p3_out(const float* __restrict__ x,
                                              const float* __restrict__ gamma,
                                              const float* __restrict__ beta,
                                              const float* __restrict__ ws,
                                              float* __restrict__ out) {
    __shared__ float at3[64][68];    // attn^T: [k][n]
    __shared__ float gs[64][128];    // G tile: [k][o_local]
    const int tid = threadIdx.x;
    const int n0 = blockIdx.x * 64;
    const int o0 = blockIdx.y * 128;
    const int b = blockIdx.z;
    const float* attn_g = ws + OFF_ATTN;
    const float* G = ws + OFF_G;

#pragma unroll 4
    for (int it = 0; it < 16; ++it) {
        int flat = it * 256 + tid;
        int n = flat >> 6, k = flat & 63;
        at3[k][n] = attn_g[((size_t)b * NN + n0 + n) * KK + k];
    }
#pragma unroll 4
    for (int it = 0; it < 32; ++it) {
        int flat = it * 256 + tid;
        int k = flat >> 7, ol = flat & 127;
        gs[k][ol] = G[((size_t)b * KK + k) * CCH + o0 + ol];
    }
    __syncthreads();

    const int nt = tid & 15, ot = tid >> 4;   // n_base = 4*nt, o_base = 8*ot
    float acc[32];
#pragma unroll
    for (int i = 0; i < 32; ++i) acc[i] = 0.f;
#pragma unroll 4
    for (int k = 0; k < 64; ++k) {
        float4 av = *(float4*)&at3[k][4 * nt];
        float ava[4] = {av.x, av.y, av.z, av.w};
        float4 g0 = *(float4*)&gs[k][8 * ot];
        float4 g1 = *(float4*)&gs[k][8 * ot + 4];
        float gva[8] = {g0.x, g0.y, g0.z, g0.w, g1.x, g1.y, g1.z, g1.w};
#pragma unroll
        for (int i = 0; i < 4; ++i)
#pragma unroll
            for (int j = 0; j < 8; ++j)
                acc[i * 8 + j] += ava[i] * gva[j];
    }

    const int grp = (o0 >> 3) + ot;
    const float m = ws[OFF_MS + b * 32 + grp];
    const float r = ws[OFF_RS + b * 32 + grp];
#pragma unroll
    for (int j = 0; j < 8; ++j) {
        int o = o0 + 8 * ot + j;
        float gm = gamma[o] * r;
        float bt = beta[o];
        size_t base = ((size_t)(b * CCH + o)) * NN + n0 + 4 * nt;
        float4 xv = *(const float4*)&x[base];
        float4 ov;
        ov.x = xv.x + (acc[0 * 8 + j] - m) * gm + bt;
        ov.y = xv.y + (acc[1 * 8 + j] - m) * gm + bt;
        ov.z = xv.z + (acc[2 * 8 + j] - m) * gm + bt;
        ov.w = xv.w + (acc[3 * 8 + j] - m) * gm + bt;
        *(float4*)&out[base] = ov;
    }
}

extern "C" void kernel_launch(void* const* d_in, const int* in_sizes, int n_in,
                              void* d_out, int out_size, void* d_ws, size_t ws_size,
                              hipStream_t stream) {
    (void)in_sizes; (void)n_in; (void)out_size; (void)ws_size;
    const float* x       = (const float*)d_in[0];
    const float* centers = (const float*)d_in[1];
    const float* dw_w    = (const float*)d_in[2];
    const float* dw_b    = (const float*)d_in[3];
    const float* pw_w    = (const float*)d_in[4];
    const float* pw_b    = (const float*)d_in[5];
    const float* gn_g    = (const float*)d_in[6];
    const float* gn_b    = (const float*)d_in[7];
    float* out = (float*)d_out;
    float* ws  = (float*)d_ws;

    // zero the atomic-accumulated regions (clu + M + abar, contiguous)
    hipMemsetAsync(ws + OFF_CLU, 0, (OFF_REF - OFF_CLU) * sizeof(float), stream);

    p0_prep<<<256, 256, 0, stream>>>(centers, pw_w, ws);
    p1_attn<<<dim3(256, 8), 256, 0, stream>>>(x, ws);
    p2_dw<<<dim3(4, 8), 256, 0, stream>>>(dw_w, dw_b, ws);
    p2_g<<<dim3(64, 8), 256, 0, stream>>>(pw_b, ws);
    p2_stats<<<8, 256, 0, stream>>>(ws);
    p3_out<<<dim3(256, 2, 8), 256, 0, stream>>>(x, gn_g, gn_b, ws, out);
}

// Round 2
// 574.452 us; speedup vs baseline: 1.7620x; 1.7620x over previous
//
#include <hip/hip_runtime.h>
#include <math.h>

#define BB 8
#define CCH 256
#define NN 16384
#define KK 64
#define SEGS 64
#define SCALE 0.0625f   // C^-0.5

// ---------------- workspace layout (float-slot offsets) ----------------
constexpr size_t OFF_ATTN = 0;                       // f32 B*N*K          = 8388608
constexpr size_t OFF_CTT  = 8388608;                 // f32 C*K            = 16384   centers^T [c][k]
constexpr size_t OFF_PWT  = OFF_CTT + 16384;         // f32 C*C            = 65536   pw_w^T [c][o]
constexpr size_t OFF_CLUP = OFF_PWT + 65536;         // bf16 SEGS*B*K*C    = 8388608 us = 4194304 slots
constexpr size_t OFF_MP   = OFF_CLUP + 4194304;      // bf16 SEGS*B*K*K    = 2097152 us = 1048576 slots
constexpr size_t OFF_ABP  = OFF_MP + 1048576;        // f32 SEGS*B*K       = 32768
constexpr size_t OFF_CLUS = OFF_ABP + 32768;         // f32 B*K*C          = 131072
constexpr size_t OFF_MS2  = OFF_CLUS + 131072;       // f32 B*K*K          = 32768
constexpr size_t OFF_ABS2 = OFF_MS2 + 32768;         // f32 B*K            = 512
constexpr size_t OFF_REF  = OFF_ABS2 + 512;          // f32 B*K*C          = 131072
constexpr size_t OFF_G    = OFF_REF + 131072;        // f32 B*K*C          = 131072
constexpr size_t OFF_MU   = OFF_G + 131072;          // f32 B*32
constexpr size_t OFF_RS   = OFF_MU + 256;            // f32 B*32
// total ≈ 14.2M float slots ≈ 56.7 MB

__device__ __forceinline__ unsigned short f2bf(float f) {
    unsigned int x = __float_as_uint(f);
    unsigned int r = (x + 0x7FFFu + ((x >> 16) & 1u)) >> 16;
    return (unsigned short)r;
}
__device__ __forceinline__ float bf2f(unsigned short u) {
    return __uint_as_float(((unsigned int)u) << 16);
}

// ---------- P0: transpose centers and pw_w ----------
__global__ __launch_bounds__(256) void p0_prep(const float* __restrict__ centers,
                                               const float* __restrict__ pw_w,
                                               float* __restrict__ ws) {
    int idx = blockIdx.x * 256 + threadIdx.x;   // 0..65535
    if (idx < 16384) {
        int c = idx >> 6, k = idx & 63;
        ws[OFF_CTT + idx] = centers[k * CCH + c];
    }
    int c = idx >> 8, o = idx & 255;
    ws[OFF_PWT + idx] = pw_w[o * CCH + c];
}

// ---------- P1: sim -> softmax -> attn ; register-resident clu/M/abar partials, NO atomics ----------
__global__ __launch_bounds__(256, 2) void p1_attn(const float* __restrict__ x,
                                                  float* __restrict__ ws) {
    __shared__ float xs[64][68];   // x chunk, c-major [c_local][n]
    __shared__ float cs[64][68];   // centers chunk [c_local][k]
    __shared__ float at[64][68];   // sim -> attn [n][k]
    __shared__ float red[64][4];
    __shared__ float red2[64][4];

    const int tid = threadIdx.x;
    const int b   = blockIdx.y;
    const int seg = blockIdx.x;        // 0..63
    const int nb0 = seg * 256;

    const int nt = tid & 15, kt = tid >> 4;    // sim tile: n=4nt+i, k=4kt+j
    const int kq = tid & 15, cg = tid >> 4;    // clu tile: k=4kq+i, c_loc=16*j4+cg
    const int lc = tid >> 2, lnq = tid & 3;    // staging loads

    const float* ctT = ws + OFF_CTT;
    float* attn_g = ws + OFF_ATTN;

    float cl_acc[4][16];               // [i -> k][jj -> c=16*jj+cg]
    float m_acc[4][4];                 // k2=4*kt+i, k1=4*kq+j  (kt==tid>>4, kq==tid&15)
    float ab_acc = 0.f;
#pragma unroll
    for (int i = 0; i < 4; ++i) {
#pragma unroll
        for (int j = 0; j < 16; ++j) cl_acc[i][j] = 0.f;
#pragma unroll
        for (int j = 0; j < 4; ++j) m_acc[i][j] = 0.f;
    }

    for (int sub = 0; sub < 4; ++sub) {
        const int ns0 = nb0 + sub * 64;

        // ---- SIM: s = x^T @ centers^T, 4 c-chunks of 64 ----
        float s_acc[4][4];
#pragma unroll
        for (int i = 0; i < 4; ++i)
#pragma unroll
            for (int j = 0; j < 4; ++j) s_acc[i][j] = 0.f;

        for (int cc = 0; cc < 4; ++cc) {
            __syncthreads();
            {
                const float* xrow = x + ((size_t)(b * CCH + cc * 64 + lc)) * NN + ns0;
                const float* crow = ctT + (size_t)(cc * 64 + lc) * KK;
#pragma unroll
                for (int m = 0; m < 4; ++m) {
                    float4 v = *(const float4*)&xrow[4 * lnq + 16 * m];
                    *(float4*)&xs[lc][4 * lnq + 16 * m] = v;
                    float4 w = *(const float4*)&crow[4 * lnq + 16 * m];
                    *(float4*)&cs[lc][4 * lnq + 16 * m] = w;
                }
            }
            __syncthreads();
#pragma unroll 8
            for (int c = 0; c < 64; ++c) {
                float4 xv = *(float4*)&xs[c][4 * nt];
                float4 cv = *(float4*)&cs[c][4 * kt];
                float xa[4] = {xv.x, xv.y, xv.z, xv.w};
                float ca[4] = {cv.x, cv.y, cv.z, cv.w};
#pragma unroll
                for (int i = 0; i < 4; ++i)
#pragma unroll
                    for (int j = 0; j < 4; ++j)
                        s_acc[i][j] += xa[i] * ca[j];
            }
        }
        // write scaled sims to at[n][k]
#pragma unroll
        for (int i = 0; i < 4; ++i) {
            float4 v = make_float4(s_acc[i][0] * SCALE, s_acc[i][1] * SCALE,
                                   s_acc[i][2] * SCALE, s_acc[i][3] * SCALE);
            *(float4*)&at[4 * nt + i][4 * kt] = v;
        }
        __syncthreads();

        // ---- softmax: 4 threads per row ----
        {
            const int rn = tid >> 2, q = tid & 3;
            float e[16];
#pragma unroll
            for (int m = 0; m < 4; ++m) {
                float4 v = *(float4*)&at[rn][q * 16 + 4 * m];
                e[4 * m + 0] = v.x; e[4 * m + 1] = v.y; e[4 * m + 2] = v.z; e[4 * m + 3] = v.w;
            }
            float lmax = -1e30f;
#pragma unroll
            for (int t = 0; t < 16; ++t) lmax = fmaxf(lmax, e[t]);
            red[rn][q] = lmax;
            __syncthreads();
            float mx = fmaxf(fmaxf(red[rn][0], red[rn][1]), fmaxf(red[rn][2], red[rn][3]));
            float ls = 0.f;
#pragma unroll
            for (int t = 0; t < 16; ++t) { e[t] = __expf(e[t] - mx); ls += e[t]; }
            red2[rn][q] = ls;
            __syncthreads();
            float rinv = 1.f / (red2[rn][0] + red2[rn][1] + red2[rn][2] + red2[rn][3]);
            float* gdst = attn_g + ((size_t)b * NN + ns0 + rn) * KK + q * 16;
#pragma unroll
            for (int m = 0; m < 4; ++m) {
                float4 v = make_float4(e[4 * m] * rinv, e[4 * m + 1] * rinv,
                                       e[4 * m + 2] * rinv, e[4 * m + 3] * rinv);
                *(float4*)&at[rn][q * 16 + 4 * m] = v;
                *(float4*)&gdst[4 * m] = v;
            }
        }
        __syncthreads();

        // ---- abar partial (k = tid&63, quarter of rows) ----
        {
            const int q4 = tid >> 6, kk = tid & 63;
#pragma unroll 8
            for (int t = 0; t < 16; ++t) ab_acc += at[q4 * 16 + t][kk];
        }

        // ---- M partial: m_acc[k2][k1] += a[n][k2]*a[n][k1] ----
#pragma unroll 8
        for (int n = 0; n < 64; ++n) {
            float4 a2 = *(float4*)&at[n][4 * kt];
            float4 a1 = *(float4*)&at[n][4 * kq];
            float a2a[4] = {a2.x, a2.y, a2.z, a2.w};
            float a1a[4] = {a1.x, a1.y, a1.z, a1.w};
#pragma unroll
            for (int i = 0; i < 4; ++i)
#pragma unroll
                for (int j = 0; j < 4; ++j)
                    m_acc[i][j] += a2a[i] * a1a[j];
        }

        // ---- CLU: cl_acc[k][c] += a[n][k]*x[n][c]; chunk 3 still in xs ----
#pragma unroll
        for (int ccl = 0; ccl < 4; ++ccl) {
            const int cc = (ccl + 3) & 3;
            if (ccl != 0) {
                __syncthreads();
                const float* xrow = x + ((size_t)(b * CCH + cc * 64 + lc)) * NN + ns0;
#pragma unroll
                for (int m = 0; m < 4; ++m) {
                    float4 v = *(const float4*)&xrow[4 * lnq + 16 * m];
                    *(float4*)&xs[lc][4 * lnq + 16 * m] = v;
                }
                __syncthreads();
            }
#pragma unroll 8
            for (int n = 0; n < 64; ++n) {
                float4 av = *(float4*)&at[n][4 * kq];
                float ava[4] = {av.x, av.y, av.z, av.w};
                float xv0 = xs[cg][n];
                float xv1 = xs[16 + cg][n];
                float xv2 = xs[32 + cg][n];
                float xv3 = xs[48 + cg][n];
#pragma unroll
                for (int i = 0; i < 4; ++i) {
                    cl_acc[i][cc * 4 + 0] += ava[i] * xv0;
                    cl_acc[i][cc * 4 + 1] += ava[i] * xv1;
                    cl_acc[i][cc * 4 + 2] += ava[i] * xv2;
                    cl_acc[i][cc * 4 + 3] += ava[i] * xv3;
                }
            }
        }
    }

    // ---- writeout: clu partial (bf16, staged via LDS for coalescing) ----
    {
        unsigned short* stg = (unsigned short*)&xs[0][0];
        unsigned int* gbase = (unsigned int*)(ws + OFF_CLUP) + (size_t)(seg * BB + b) * 64 * 128;
#pragma unroll
        for (int cc = 0; cc < 4; ++cc) {
            __syncthreads();
#pragma unroll
            for (int i = 0; i < 4; ++i)
#pragma unroll
                for (int j4 = 0; j4 < 4; ++j4)
                    stg[(4 * kq + i) * 64 + 16 * j4 + cg] = f2bf(cl_acc[i][cc * 4 + j4]);
            __syncthreads();
            const unsigned int* s32 = (const unsigned int*)stg;
#pragma unroll
            for (int m = 0; m < 8; ++m) {
                int flat = m * 256 + tid;
                int k = flat >> 5, ch = flat & 31;
                gbase[(size_t)k * 128 + cc * 32 + ch] = s32[flat];
            }
        }
    }
    // ---- writeout: M partial (bf16 packed) ----
    {
        unsigned short* mp = (unsigned short*)(ws + OFF_MP) + (size_t)(seg * BB + b) * 4096;
#pragma unroll
        for (int i = 0; i < 4; ++i) {
            unsigned int lo = (unsigned int)f2bf(m_acc[i][0]) | ((unsigned int)f2bf(m_acc[i][1]) << 16);
            unsigned int hi = (unsigned int)f2bf(m_acc[i][2]) | ((unsigned int)f2bf(m_acc[i][3]) << 16);
            uint2 val; val.x = lo; val.y = hi;
            *(uint2*)&mp[(4 * kt + i) * 64 + 4 * kq] = val;
        }
    }
    // ---- writeout: abar partial ----
    __syncthreads();
    red[tid & 63][tid >> 6] = ab_acc;
    __syncthreads();
    if (tid < 64)
        ws[OFF_ABP + (size_t)(seg * BB + b) * KK + tid] =
            red[tid][0] + red[tid][1] + red[tid][2] + red[tid][3];
}

// ---------- P1.5: reduce partials over 64 segs ----------
__global__ __launch_bounds__(256) void p15_reduce(float* __restrict__ ws) {
    const int blk = blockIdx.x;
    const unsigned short* clu_p = (const unsigned short*)(ws + OFF_CLUP);
    const unsigned short* m_p   = (const unsigned short*)(ws + OFF_MP);
    if (blk < 512) {
        const int b = blk >> 6, k = blk & 63, c = threadIdx.x;
        float s = 0.f;
#pragma unroll 8
        for (int seg = 0; seg < SEGS; ++seg)
            s += bf2f(clu_p[((size_t)((seg * BB + b) * KK + k)) * CCH + c]);
        ws[OFF_CLUS + ((size_t)(b * KK + k)) * CCH + c] = s;
    } else {
        const int t = blk - 512;
        const int b = t >> 3, part = t & 7;
#pragma unroll
        for (int it = 0; it < 2; ++it) {
            int idx = part * 512 + it * 256 + threadIdx.x;
            float s = 0.f;
#pragma unroll 8
            for (int seg = 0; seg < SEGS; ++seg)
                s += bf2f(m_p[(size_t)(seg * BB + b) * 4096 + idx]);
            ws[OFF_MS2 + (size_t)b * 4096 + idx] = s;
        }
        if (part == 0 && threadIdx.x < 64) {
            float s = 0.f;
#pragma unroll 8
            for (int seg = 0; seg < SEGS; ++seg)
                s += ws[OFF_ABP + (size_t)(seg * BB + b) * KK + threadIdx.x];
            ws[OFF_ABS2 + b * KK + threadIdx.x] = s;
        }
    }
}

// ---------- P2a: depthwise 7x7 + bias + silu on 8x8 cluster grid ----------
__global__ __launch_bounds__(256) void p2_dw(const float* __restrict__ dw_w,
                                             const float* __restrict__ dw_b,
                                             float* __restrict__ ws) {
    __shared__ float clu_s[64][256];
    const int b = blockIdx.y;
    const int kq = blockIdx.x;
    const int tid = threadIdx.x;
    float* ref = ws + OFF_REF;

    for (int k = 0; k < 64; ++k)
        clu_s[k][tid] = ws[OFF_CLUS + ((size_t)(b * KK + k)) * CCH + tid];
    float w[49];
#pragma unroll
    for (int t = 0; t < 49; ++t) w[t] = dw_w[tid * 49 + t];
    float bias = dw_b[tid];
    __syncthreads();

    for (int it = 0; it < 16; ++it) {
        int k = kq * 16 + it;
        int ky = k >> 3, kx = k & 7;
        float v = 0.f;
#pragma unroll
        for (int dy = 0; dy < 7; ++dy) {
            int yy = ky + dy - 3;
            if (yy < 0 || yy > 7) continue;
#pragma unroll
            for (int dx = 0; dx < 7; ++dx) {
                int xx = kx + dx - 3;
                if (xx < 0 || xx > 7) continue;
                v += clu_s[yy * 8 + xx][tid] * w[dy * 7 + dx];
            }
        }
        v += bias;
        float sv = v / (1.f + expf(-v));
        ref[((size_t)b * KK + k) * CCH + tid] = sv;
    }
}

// ---------- P2b: G[b,k,o] = sum_c refined * pw_w[o,c] + pw_b[o] ----------
__global__ __launch_bounds__(256) void p2_g(const float* __restrict__ pw_b,
                                            float* __restrict__ ws) {
    __shared__ float rs[256];
    const int b = blockIdx.y, k = blockIdx.x, tid = threadIdx.x;
    const float* ref = ws + OFF_REF;
    const float* pwT = ws + OFF_PWT;
    float* G = ws + OFF_G;
    rs[tid] = ref[((size_t)b * KK + k) * CCH + tid];
    __syncthreads();
    float g = pw_b[tid];
#pragma unroll 8
    for (int c = 0; c < 256; ++c)
        g += rs[c] * pwT[c * CCH + tid];
    G[((size_t)b * KK + k) * CCH + tid] = g;
}

// ---------- P2c: analytic group-norm statistics ----------
__global__ __launch_bounds__(256) void p2_stats(float* __restrict__ ws) {
    __shared__ float Ms[4096];
    __shared__ float abs_[64];
    __shared__ float mu_s[256];
    __shared__ float q_s[256];
    const int b = blockIdx.x, tid = threadIdx.x;
    const float* G = ws + OFF_G;

    for (int it = 0; it < 16; ++it) {
        int idx = it * 256 + tid;
        Ms[idx] = ws[OFF_MS2 + (size_t)b * 4096 + idx] * (1.0f / 16384.0f);
    }
    if (tid < 64)
        abs_[tid] = ws[OFF_ABS2 + b * KK + tid] * (1.0f / 16384.0f);
    __syncthreads();

    float gv[64];
#pragma unroll 8
    for (int k = 0; k < 64; ++k) gv[k] = G[((size_t)b * KK + k) * CCH + tid];
    float mu = 0.f;
#pragma unroll 8
    for (int k = 0; k < 64; ++k) mu += abs_[k] * gv[k];
    float q = 0.f;
    for (int k = 0; k < 64; ++k) {
        float t = 0.f;
#pragma unroll 8
        for (int k2 = 0; k2 < 64; ++k2) t += Ms[k * 64 + k2] * gv[k2];
        q += t * gv[k];
    }
    mu_s[tid] = mu;
    q_s[tid] = q;
    __syncthreads();
    if (tid < 32) {
        float m = 0.f, e = 0.f;
#pragma unroll
        for (int j = 0; j < 8; ++j) { m += mu_s[tid * 8 + j]; e += q_s[tid * 8 + j]; }
        m *= 0.125f; e *= 0.125f;
        float var = e - m * m;
        ws[OFF_MU + b * 32 + tid] = m;
        ws[OFF_RS + b * 32 + tid] = rsqrtf(fmaxf(var, 0.f) + 1e-5f);
    }
}

// ---------- P3: y = attn @ G ; out = x + (y-mu)*rsig*gamma + beta ----------
__global__ __launch_bounds__(256) void p3_out(const float* __restrict__ x,
                                              const float* __restrict__ gamma,
                                              const float* __restrict__ beta,
                                              const float* __restrict__ ws,
                                              float* __restrict__ out) {
    __shared__ float at3[64][68];    // attn^T: [k][n]
    __shared__ float gs[64][128];    // G tile: [k][o_local]
    const int tid = threadIdx.x;
    const int n0 = blockIdx.x * 64;
    const int o0 = blockIdx.y * 128;
    const int b = blockIdx.z;
    const float* attn_g = ws + OFF_ATTN;
    const float* G = ws + OFF_G;

#pragma unroll 4
    for (int it = 0; it < 16; ++it) {
        int flat = it * 256 + tid;
        int n = flat >> 6, k = flat & 63;
        at3[k][n] = attn_g[((size_t)b * NN + n0 + n) * KK + k];
    }
#pragma unroll 4
    for (int it = 0; it < 32; ++it) {
        int flat = it * 256 + tid;
        int k = flat >> 7, ol = flat & 127;
        gs[k][ol] = G[((size_t)b * KK + k) * CCH + o0 + ol];
    }
    __syncthreads();

    const int nt = tid & 15, ot = tid >> 4;
    float acc[32];
#pragma unroll
    for (int i = 0; i < 32; ++i) acc[i] = 0.f;
#pragma unroll 4
    for (int k = 0; k < 64; ++k) {
        float4 av = *(float4*)&at3[k][4 * nt];
        float ava[4] = {av.x, av.y, av.z, av.w};
        float4 g0 = *(float4*)&gs[k][8 * ot];
        float4 g1 = *(float4*)&gs[k][8 * ot + 4];
        float gva[8] = {g0.x, g0.y, g0.z, g0.w, g1.x, g1.y, g1.z, g1.w};
#pragma unroll
        for (int i = 0; i < 4; ++i)
#pragma unroll
            for (int j = 0; j < 8; ++j)
                acc[i * 8 + j] += ava[i] * gva[j];
    }

    const int grp = (o0 >> 3) + ot;
    const float m = ws[OFF_MU + b * 32 + grp];
    const float r = ws[OFF_RS + b * 32 + grp];
#pragma unroll
    for (int j = 0; j < 8; ++j) {
        int o = o0 + 8 * ot + j;
        float gm = gamma[o] * r;
        float bt = beta[o];
        size_t base = ((size_t)(b * CCH + o)) * NN + n0 + 4 * nt;
        float4 xv = *(const float4*)&x[base];
        float4 ov;
        ov.x = xv.x + (acc[0 * 8 + j] - m) * gm + bt;
        ov.y = xv.y + (acc[1 * 8 + j] - m) * gm + bt;
        ov.z = xv.z + (acc[2 * 8 + j] - m) * gm + bt;
        ov.w = xv.w + (acc[3 * 8 + j] - m) * gm + bt;
        *(float4*)&out[base] = ov;
    }
}

extern "C" void kernel_launch(void* const* d_in, const int* in_sizes, int n_in,
                              void* d_out, int out_size, void* d_ws, size_t ws_size,
                              hipStream_t stream) {
    (void)in_sizes; (void)n_in; (void)out_size; (void)ws_size;
    const float* x       = (const float*)d_in[0];
    const float* centers = (const float*)d_in[1];
    const float* dw_w    = (const float*)d_in[2];
    const float* dw_b    = (const float*)d_in[3];
    const float* pw_b    = (const float*)d_in[5];
    const float* gn_g    = (const float*)d_in[6];
    const float* gn_b    = (const float*)d_in[7];
    const float* pw_w    = (const float*)d_in[4];
    float* out = (float*)d_out;
    float* ws  = (float*)d_ws;

    p0_prep<<<256, 256, 0, stream>>>(centers, pw_w, ws);
    p1_attn<<<dim3(64, 8), 256, 0, stream>>>(x, ws);
    p15_reduce<<<576, 256, 0, stream>>>(ws);
    p2_dw<<<dim3(4, 8), 256, 0, stream>>>(dw_w, dw_b, ws);
    p2_g<<<dim3(64, 8), 256, 0, stream>>>(pw_b, ws);
    p2_stats<<<8, 256, 0, stream>>>(ws);
    p3_out<<<dim3(256, 2, 8), 256, 0, stream>>>(x, gn_g, gn_b, ws, out);
}